// Round 6
// baseline (429.419 us; speedup 1.0000x reference)
//
#include <hip/hip_runtime.h>
#include <hip/hip_bf16.h>

#define NREF  4096
#define NTR   8192
#define NCOMB 12288
#define DIN   384
#define HID   1024
#define NE    4
#define ESTR  3456   // per-element compact row stride (count~3072, +pad)
#define MT    (ESTR / 128)   // 27 m-tiles

typedef __attribute__((ext_vector_type(8))) short bf16x8;
typedef __attribute__((ext_vector_type(4))) short s16x4;
typedef __attribute__((ext_vector_type(4))) float f32x4;

// ---------------------------------------------------------------------------
// ws layout (bytes)
#define WS_CNT    0
#define WS_RCNT   16
#define WS_POST   256                                   // NTR*4 = 32768
#define WS_RIDX   (WS_POST + NTR*4)                     // NE*NREF*4 = 65536
#define WS_COMB   (WS_RIDX + NE*NREF*4)                 // NE*NCOMB*4 = 196608
#define WS_W1TH   524288
#define WS_W1TL   (WS_W1TH + NE*DIN*HID*2)              // +3145728
#define WS_XGH    (WS_W1TL + NE*DIN*HID*2)              // 6815744
#define WS_XGL    (WS_XGH + NE*ESTR*DIN*2)              // +10616832
#define WS_W2TH   WS_XGH                                 // alias: Xg dead after k_l1
#define WS_W2TL   WS_XGL
#define WS_H1H    (WS_XGL + NE*ESTR*DIN*2)              // 28049408
#define WS_H1L    (WS_H1H + (size_t)NE*ESTR*HID*2)      // +28311552
#define WS_HFIN   (WS_H1L + (size_t)NE*ESTR*HID*2)      // 84672512 (+55296)
// total ~84.8 MB
// ---------------------------------------------------------------------------

__device__ __forceinline__ short f2bf(float f) {
    unsigned u = __builtin_bit_cast(unsigned, f);
    unsigned r = (u + 0x7FFF + ((u >> 16) & 1)) >> 16;   // RNE
    return (short)r;
}
__device__ __forceinline__ float bf2f(short s) {
    unsigned u = ((unsigned)(unsigned short)s) << 16;
    return __builtin_bit_cast(float, u);
}
__device__ __forceinline__ void gload16(const void* g, void* l) {
    __builtin_amdgcn_global_load_lds(
        (const __attribute__((address_space(1))) void*)g,
        (__attribute__((address_space(3))) void*)l, 16, 0, 0);
}
__device__ __forceinline__ float celu1(float v) {
    return v > 0.f ? v : (expf(v) - 1.f);
}

// ---------------------------------------------------------------------------
__global__ void k_compact(const int* __restrict__ lr, const int* __restrict__ lt,
                          int* cnt, int* rcnt, int* comb, int* ridxP, int* post) {
    int i = blockIdx.x * 256 + threadIdx.x;
    if (i < NREF) {
        int e = lr[i] - 1;
        int q = atomicAdd(&cnt[e], 1);
        comb[e * NCOMB + q] = i;
        int p = atomicAdd(&rcnt[e], 1);
        ridxP[e * NREF + p] = i | (q << 16);     // ref id | compact pos
    } else if (i < NCOMB) {
        int t = i - NREF;
        int e = lt[t] - 1;
        int q = atomicAdd(&cnt[e], 1);
        comb[e * NCOMB + q] = NREF + t;
        post[t] = q;                              // train compact pos
    }
}

// ---------------------------------------------------------------------------
// Fused prep: [0,1536) W1 transpose+split; [1536,4992) x gather+split;
// [4992,4996) zero hfin.
#define PREP_TR1  1536
#define PREP_GAT  (PREP_TR1 + ESTR/4*NE)
#define PREP_ZERO (PREP_GAT + 4)
__global__ __launch_bounds__(256) void k_prep(
    const float* __restrict__ W1,
    const float* __restrict__ xr, const float* __restrict__ xt,
    const int* __restrict__ cnt, const int* __restrict__ comb,
    short* __restrict__ W1Th, short* __restrict__ W1Tl,
    short* __restrict__ XgH, short* __restrict__ XgL,
    float* __restrict__ hfinC) {
    __shared__ float s[32][33];
    int b = blockIdx.x;
    if (b < PREP_TR1) {
        int e = b / 384, r = b % 384;
        int n0 = (r & 31) * 32, k0 = (r >> 5) * 32;
        int tx = threadIdx.x & 31, ty = threadIdx.x >> 5;
        const float* src = W1 + (size_t)e * DIN * HID;
#pragma unroll
        for (int i = 0; i < 32; i += 8)
            s[ty + i][tx] = src[(size_t)(k0 + ty + i) * HID + n0 + tx];
        __syncthreads();
#pragma unroll
        for (int i = 0; i < 32; i += 8) {
            float v = s[tx][ty + i];
            short hb = f2bf(v);
            short lb = f2bf(v - bf2f(hb));
            size_t o = ((size_t)e * HID + n0 + ty + i) * DIN + k0 + tx;
            W1Th[o] = hb;
            W1Tl[o] = lb;
        }
    } else if (b < PREP_GAT) {
        int b2 = b - PREP_TR1;
        int e = b2 / (ESTR / 4);
        int m = (b2 % (ESTR / 4)) * 4 + (threadIdx.x >> 6);
        int lane = threadIdx.x & 63;
        size_t dst = ((size_t)e * ESTR + m) * DIN;
        if (m < cnt[e]) {
            int g = comb[e * NCOMB + m];
            const float* src = (g < NREF) ? (xr + (size_t)g * DIN)
                                          : (xt + (size_t)(g - NREF) * DIN);
#pragma unroll
            for (int c = lane * 2, it = 0; it < 3; c += 128, ++it) {
                float2 v = *(const float2*)(src + c);
                short2 h, l;
                h.x = f2bf(v.x); l.x = f2bf(v.x - bf2f(h.x));
                h.y = f2bf(v.y); l.y = f2bf(v.y - bf2f(h.y));
                *(short2*)(XgH + dst + c) = h;
                *(short2*)(XgL + dst + c) = l;
            }
        } else {
#pragma unroll
            for (int c = lane * 2, it = 0; it < 3; c += 128, ++it) {
                *(short2*)(XgH + dst + c) = short2{0, 0};
                *(short2*)(XgL + dst + c) = short2{0, 0};
            }
        }
    } else {
        int idx = (b - PREP_GAT) * 1024 + threadIdx.x;
        if (idx * 4 < NE * ESTR) {
            f32x4 z = {0.f, 0.f, 0.f, 0.f};
            *(f32x4*)(hfinC + idx * 4) = z;
        }
    }
}

// W2 transpose + hi/lo split with permuted K. pi(k)=(k&~63)|((k&15)<<2)|((k>>4)&3)
__global__ __launch_bounds__(256) void k_tr2(const float* __restrict__ W,
                                             short* __restrict__ Th,
                                             short* __restrict__ Tl) {
    int e = blockIdx.z;
    __shared__ float s[32][33];
    int tx = threadIdx.x & 31, ty = threadIdx.x >> 5;
    int k0 = blockIdx.y * 32, n0 = blockIdx.x * 32;
    const float* src = W + (size_t)e * HID * HID;
#pragma unroll
    for (int i = 0; i < 32; i += 8)
        s[ty + i][tx] = src[(size_t)(k0 + ty + i) * HID + n0 + tx];
    __syncthreads();
    int k = k0 + tx;
    int kk = (k & ~63) | ((k & 15) << 2) | ((k >> 4) & 3);
#pragma unroll
    for (int i = 0; i < 32; i += 8) {
        float v = s[tx][ty + i];
        short hb = f2bf(v);
        short lb = f2bf(v - bf2f(hb));
        size_t o = ((size_t)e * HID + n0 + ty + i) * HID + kk;
        Th[o] = hb;
        Tl[o] = lb;
    }
}

// ---------------------------------------------------------------------------
// Shared fragment-read helper (per-slot layout: Ah@0, Al@8K, Bh@16K, Bl@24K;
// 64B rows, XOR-swizzled 16B chunks)
#define READ_FRAGS(slotp)                                                     \
    bf16x8 ah[4], al[4], bh[4], bl[4];                                        \
    _Pragma("unroll")                                                         \
    for (int m = 0; m < 4; m++) {                                             \
        int row = wr * 64 + m * 16 + (lane & 15);                             \
        int off = row * 64 + ((((lane >> 4) ^ ((row >> 1) & 3))) << 4);       \
        ah[m] = *(const bf16x8*)((slotp) + off);                              \
        al[m] = *(const bf16x8*)((slotp) + 8192 + off);                       \
    }                                                                         \
    _Pragma("unroll")                                                         \
    for (int n = 0; n < 4; n++) {                                             \
        int row = wc * 64 + n * 16 + (lane & 15);                             \
        int off = row * 64 + ((((lane >> 4) ^ ((row >> 1) & 3))) << 4);       \
        bh[n] = *(const bf16x8*)((slotp) + 16384 + off);                      \
        bl[n] = *(const bf16x8*)((slotp) + 24576 + off);                      \
    }

#define DO_MFMA()                                                             \
    _Pragma("unroll")                                                         \
    for (int m = 0; m < 4; m++)                                               \
        _Pragma("unroll")                                                     \
        for (int n = 0; n < 4; n++) {                                         \
            acc[m][n] = __builtin_amdgcn_mfma_f32_16x16x32_bf16(ah[m], bh[n], acc[m][n], 0, 0, 0); \
            acc[m][n] = __builtin_amdgcn_mfma_f32_16x16x32_bf16(al[m], bh[n], acc[m][n], 0, 0, 0); \
            acc[m][n] = __builtin_amdgcn_mfma_f32_16x16x32_bf16(ah[m], bl[n], acc[m][n], 0, 0, 0); \
        }

// ---------------------------------------------------------------------------
// Layer 1: H1C = celu(Xg @ W1 + b1). 128x128 tile, BK=32, 4 waves,
// 3-slot LDS ring, depth-2 prefetch, counted vmcnt, 1 raw barrier/iter.
__global__ __launch_bounds__(256) void k_l1(
    const short* __restrict__ XgH, const short* __restrict__ XgL,
    const short* __restrict__ W1Th, const short* __restrict__ W1Tl,
    const float* __restrict__ b1, const int* __restrict__ cnt,
    short* __restrict__ H1h, short* __restrict__ H1l) {
    int bid = blockIdx.x;
    int n0 = (bid & 7) * 128;
    int rest = bid >> 3;
    int e = rest / MT;
    int count = cnt[e];
    int m0 = (rest % MT) * 128;
    if (m0 >= count) return;

    extern __shared__ __align__(16) char smem[];   // 3 * 32768
    int t = threadIdx.x, w = t >> 6, lane = t & 63;
    int wr = w >> 1, wc = w & 1;

    int srow = t >> 2, sx = t & 3, fB = (srow >> 1) & 3;
    size_t aoff0 = ((size_t)e * ESTR + m0 + srow) * DIN + (sx ^ fB) * 8;
    size_t aoff1 = aoff0 + (size_t)64 * DIN;
    size_t boff0 = ((size_t)e * HID + n0 + srow) * DIN + (sx ^ fB) * 8;
    size_t boff1 = boff0 + (size_t)64 * DIN;
    char* ldsW = smem + w * 1024;   // wave-uniform base; HW adds lane*16

#define STAGE1(T, SL) do { int kk = (T) * 32; char* Ld = ldsW + (SL) * 32768; \
        gload16(XgH  + aoff0 + kk, Ld + 0);     gload16(XgH  + aoff1 + kk, Ld + 4096);  \
        gload16(XgL  + aoff0 + kk, Ld + 8192);  gload16(XgL  + aoff1 + kk, Ld + 12288); \
        gload16(W1Th + boff0 + kk, Ld + 16384); gload16(W1Th + boff1 + kk, Ld + 20480); \
        gload16(W1Tl + boff0 + kk, Ld + 24576); gload16(W1Tl + boff1 + kk, Ld + 28672); } while (0)

    f32x4 acc[4][4] = {};
    const int NT = DIN / 32;   // 12

    STAGE1(0, 0);
    STAGE1(1, 1);
    for (int kt = 0; kt < NT - 1; ++kt) {
        __builtin_amdgcn_sched_barrier(0);
        asm volatile("s_waitcnt vmcnt(8)" ::: "memory");
        __builtin_amdgcn_s_barrier();
        __builtin_amdgcn_sched_barrier(0);
        if (kt + 2 < NT) STAGE1(kt + 2, (kt + 2) % 3);
        char* slotp = smem + (kt % 3) * 32768;
        READ_FRAGS(slotp)
        DO_MFMA()
    }
    __builtin_amdgcn_sched_barrier(0);
    asm volatile("s_waitcnt vmcnt(0)" ::: "memory");
    __builtin_amdgcn_s_barrier();
    __builtin_amdgcn_sched_barrier(0);
    {
        char* slotp = smem + ((NT - 1) % 3) * 32768;
        READ_FRAGS(slotp)
        DO_MFMA()
    }
#undef STAGE1

    // epilogue: bias+celu, split, permuted short4 store
    int q = lane & 15;
    float bb[4];
#pragma unroll
    for (int n = 0; n < 4; n++) bb[n] = b1[e * HID + n0 + wc * 64 + n * 16 + q];
#pragma unroll
    for (int m = 0; m < 4; m++) {
        int rbase = m0 + wr * 64 + m * 16 + (lane >> 4) * 4;
#pragma unroll
        for (int r = 0; r < 4; r++) {
            int row = rbase + r;
            if (row < count) {
                s16x4 hv, lv;
#pragma unroll
                for (int n = 0; n < 4; n++) {
                    float v = celu1(acc[m][n][r] + bb[n]);
                    hv[n] = f2bf(v);
                    lv[n] = f2bf(v - bf2f(hv[n]));
                }
                size_t o = ((size_t)e * ESTR + row) * HID + n0 + wc * 64 + q * 4;
                *(s16x4*)(H1h + o) = hv;
                *(s16x4*)(H1l + o) = lv;
            }
        }
    }
}

// ---------------------------------------------------------------------------
// Layers 2+3 fused. Same pipelined K-loop, K=1024.
__global__ __launch_bounds__(256) void k_l23(
    const short* __restrict__ H1h, const short* __restrict__ H1l,
    const short* __restrict__ W2Th, const short* __restrict__ W2Tl,
    const float* __restrict__ b2, const float* __restrict__ W3,
    const int* __restrict__ cnt, float* __restrict__ hfinC) {
    int bid = blockIdx.x;
    int n0 = (bid & 7) * 128;
    int rest = bid >> 3;
    int e = rest / MT;
    int count = cnt[e];
    int m0 = (rest % MT) * 128;
    if (m0 >= count) return;

    extern __shared__ __align__(16) char smem[];   // 3 * 32768
    int t = threadIdx.x, w = t >> 6, lane = t & 63;
    int wr = w >> 1, wc = w & 1;

    int srow = t >> 2, sx = t & 3, f0 = (srow >> 1) & 3;
    size_t aoff0 = ((size_t)e * ESTR + m0 + srow) * HID + (sx ^ f0) * 8;
    size_t aoff1 = aoff0 + (size_t)64 * HID;
    size_t boff0 = ((size_t)e * HID + n0 + srow) * HID + (sx ^ f0) * 8;
    size_t boff1 = boff0 + (size_t)64 * HID;
    char* ldsW = smem + w * 1024;

#define STAGE23(T, SL) do { int kk = (T) * 32; char* Ld = ldsW + (SL) * 32768; \
        gload16(H1h  + aoff0 + kk, Ld + 0);     gload16(H1h  + aoff1 + kk, Ld + 4096);  \
        gload16(H1l  + aoff0 + kk, Ld + 8192);  gload16(H1l  + aoff1 + kk, Ld + 12288); \
        gload16(W2Th + boff0 + kk, Ld + 16384); gload16(W2Th + boff1 + kk, Ld + 20480); \
        gload16(W2Tl + boff0 + kk, Ld + 24576); gload16(W2Tl + boff1 + kk, Ld + 28672); } while (0)

    f32x4 acc[4][4] = {};
    const int NT = HID / 32;   // 32

    STAGE23(0, 0);
    STAGE23(1, 1);
    for (int kt = 0; kt < NT - 1; ++kt) {
        __builtin_amdgcn_sched_barrier(0);
        asm volatile("s_waitcnt vmcnt(8)" ::: "memory");
        __builtin_amdgcn_s_barrier();
        __builtin_amdgcn_sched_barrier(0);
        if (kt + 2 < NT) STAGE23(kt + 2, (kt + 2) % 3);
        char* slotp = smem + (kt % 3) * 32768;
        READ_FRAGS(slotp)
        DO_MFMA()
    }
    __builtin_amdgcn_sched_barrier(0);
    asm volatile("s_waitcnt vmcnt(0)" ::: "memory");
    __builtin_amdgcn_s_barrier();
    __builtin_amdgcn_sched_barrier(0);
    {
        char* slotp = smem + ((NT - 1) % 3) * 32768;
        READ_FRAGS(slotp)
        DO_MFMA()
    }
#undef STAGE23

    // epilogue: celu + W3-weight, reduce over 128 cols of this tile
    float s[4][4] = {};
#pragma unroll
    for (int n = 0; n < 4; n++) {
        int col = n0 + wc * 64 + n * 16 + (lane & 15);
        float bbv = b2[e * HID + col];
        float w3 = W3[e * HID + col];
#pragma unroll
        for (int m = 0; m < 4; m++)
#pragma unroll
            for (int r = 0; r < 4; r++)
                s[m][r] += celu1(acc[m][n][r] + bbv) * w3;
    }
#pragma unroll
    for (int m = 0; m < 4; m++)
#pragma unroll
        for (int r = 0; r < 4; r++) {
#pragma unroll
            for (int off = 8; off > 0; off >>= 1)
                s[m][r] += __shfl_xor(s[m][r], off, 64);
        }
    if ((lane & 15) == 0) {
#pragma unroll
        for (int m = 0; m < 4; m++) {
            int rbase = m0 + wr * 64 + m * 16 + (lane >> 4) * 4;
#pragma unroll
            for (int r = 0; r < 4; r++)
                if (rbase + r < count)
                    atomicAdd(&hfinC[e * ESTR + rbase + r], s[m][r]);
        }
    }
}

// ---------------------------------------------------------------------------
__global__ __launch_bounds__(256) void k_out(
    const int* __restrict__ lt, const float* __restrict__ yref,
    const float* __restrict__ alpha, const int* __restrict__ rcnt,
    const int* __restrict__ ridxP, const int* __restrict__ post,
    const float* __restrict__ hfinC, float* __restrict__ out) {
    int t = blockIdx.x * 4 + (threadIdx.x >> 6);
    int lane = threadIdx.x & 63;
    if (t >= NTR) return;
    int lab = lt[t];
    int e = lab - 1;
    float ht = hfinC[e * ESTR + post[t]];
    float a = alpha[e];
    int n = rcnt[e];
    const int* lst = ridxP + e * NREF;
    float num = 0.f, den = 0.f;
    for (int i = lane; i < n; i += 64) {
        int pk = lst[i];
        int r = pk & 0xFFFF;
        int pq = pk >> 16;
        float d = fabsf(ht - hfinC[e * ESTR + pq]);
        float p = expf(-a * d);
        num += p * yref[r];
        den += p;
    }
#pragma unroll
    for (int o = 32; o > 0; o >>= 1) {
        num += __shfl_down(num, o, 64);
        den += __shfl_down(den, o, 64);
    }
    if (lane == 0) {
        out[t] = (float)lab;
        out[NTR + t] = num / den;
    }
}

extern "C" void kernel_launch(void* const* d_in, const int* in_sizes, int n_in,
                              void* d_out, int out_size, void* d_ws, size_t ws_size,
                              hipStream_t stream) {
    const float* xr    = (const float*)d_in[0];
    const float* yref  = (const float*)d_in[1];
    const int*   lr    = (const int*)  d_in[2];
    const float* xt    = (const float*)d_in[3];
    const int*   lt    = (const int*)  d_in[4];
    const float* W1    = (const float*)d_in[5];
    const float* b1    = (const float*)d_in[6];
    const float* W2    = (const float*)d_in[7];
    const float* b2    = (const float*)d_in[8];
    const float* W3    = (const float*)d_in[9];
    // d_in[10] = b3 (cancels in |ht-hr|), d_in[11] = alpha
    const float* alpha = (const float*)d_in[11];

    // allow 96KB dynamic LDS (capture-safe host-side attribute, idempotent)
    hipFuncSetAttribute((const void*)k_l1,
                        hipFuncAttributeMaxDynamicSharedMemorySize, 3 * 32768);
    hipFuncSetAttribute((const void*)k_l23,
                        hipFuncAttributeMaxDynamicSharedMemorySize, 3 * 32768);

    char* ws = (char*)d_ws;
    int*   cnt   = (int*)(ws + WS_CNT);
    int*   rcnt  = (int*)(ws + WS_RCNT);
    int*   post  = (int*)(ws + WS_POST);
    int*   ridxP = (int*)(ws + WS_RIDX);
    int*   comb  = (int*)(ws + WS_COMB);
    short* W1Th  = (short*)(ws + WS_W1TH);
    short* W1Tl  = (short*)(ws + WS_W1TL);
    short* XgH   = (short*)(ws + WS_XGH);
    short* XgL   = (short*)(ws + WS_XGL);
    short* W2Th  = (short*)(ws + WS_W2TH);   // aliases XgH (Xg dead after k_l1)
    short* W2Tl  = (short*)(ws + WS_W2TL);   // aliases XgL
    short* H1h   = (short*)(ws + WS_H1H);
    short* H1l   = (short*)(ws + WS_H1L);
    float* hfinC = (float*)(ws + WS_HFIN);
    float* out   = (float*)d_out;

    hipMemsetAsync(ws, 0, 32, stream);                      // cnt + rcnt

    k_compact<<<NCOMB / 256, 256, 0, stream>>>(lr, lt, cnt, rcnt, comb, ridxP, post);

    k_prep<<<PREP_ZERO, 256, 0, stream>>>(W1, xr, xt, cnt, comb,
                                          W1Th, W1Tl, XgH, XgL, hfinC);

    k_l1<<<8 * MT * NE, 256, 3 * 32768, stream>>>(XgH, XgL, W1Th, W1Tl, b1, cnt,
                                                  H1h, H1l);

    // W2 transpose AFTER k_l1 (it overwrites the Xg region)
    k_tr2<<<dim3(HID / 32, HID / 32, NE), 256, 0, stream>>>(W2, W2Th, W2Tl);

    k_l23<<<8 * MT * NE, 256, 3 * 32768, stream>>>(H1h, H1l, W2Th, W2Tl, b2, W3,
                                                   cnt, hfinC);

    k_out<<<NTR / 4, 256, 0, stream>>>(lt, yref, alpha, rcnt, ridxP, post, hfinC, out);
}

// Round 7
// 371.614 us; speedup vs baseline: 1.1556x; 1.1556x over previous
//
#include <hip/hip_runtime.h>
#include <hip/hip_bf16.h>

#define NREF  4096
#define NTR   8192
#define NCOMB 12288
#define DIN   384
#define HID   1024
#define NE    4
#define ESTR  3456   // per-element compact row stride (count~3072, +pad)
#define MT    (ESTR / 128)   // 27 m-tiles

typedef __attribute__((ext_vector_type(8))) short bf16x8;
typedef __attribute__((ext_vector_type(4))) short s16x4;
typedef __attribute__((ext_vector_type(4))) float f32x4;

// ---------------------------------------------------------------------------
// ws layout (bytes)
#define WS_CNT    0
#define WS_RCNT   16
#define WS_POST   256                                   // NTR*4 = 32768
#define WS_RIDX   (WS_POST + NTR*4)                     // NE*NREF*4 = 65536
#define WS_COMB   (WS_RIDX + NE*NREF*4)                 // NE*NCOMB*4 = 196608
#define WS_W1TH   524288
#define WS_W1TL   (WS_W1TH + NE*DIN*HID*2)              // +3145728
#define WS_XGH    (WS_W1TL + NE*DIN*HID*2)              // 6815744
#define WS_XGL    (WS_XGH + NE*ESTR*DIN*2)              // +10616832
#define WS_W2TH   WS_XGH                                 // alias: Xg dead after k_l1
#define WS_W2TL   WS_XGL
#define WS_H1H    (WS_XGL + NE*ESTR*DIN*2)              // 28049408
#define WS_H1L    (WS_H1H + (size_t)NE*ESTR*HID*2)      // +28311552
#define WS_HFIN   (WS_H1L + (size_t)NE*ESTR*HID*2)      // 84672512 (+55296)
// total ~84.8 MB
// ---------------------------------------------------------------------------

__device__ __forceinline__ short f2bf(float f) {
    unsigned u = __builtin_bit_cast(unsigned, f);
    unsigned r = (u + 0x7FFF + ((u >> 16) & 1)) >> 16;   // RNE
    return (short)r;
}
__device__ __forceinline__ float bf2f(short s) {
    unsigned u = ((unsigned)(unsigned short)s) << 16;
    return __builtin_bit_cast(float, u);
}
__device__ __forceinline__ void gload16(const void* g, void* l) {
    __builtin_amdgcn_global_load_lds(
        (const __attribute__((address_space(1))) void*)g,
        (__attribute__((address_space(3))) void*)l, 16, 0, 0);
}
__device__ __forceinline__ float celu1(float v) {
    return v > 0.f ? v : (expf(v) - 1.f);
}

// ---------------------------------------------------------------------------
__global__ void k_compact(const int* __restrict__ lr, const int* __restrict__ lt,
                          int* cnt, int* rcnt, int* comb, int* ridxP, int* post) {
    int i = blockIdx.x * 256 + threadIdx.x;
    if (i < NREF) {
        int e = lr[i] - 1;
        int q = atomicAdd(&cnt[e], 1);
        comb[e * NCOMB + q] = i;
        int p = atomicAdd(&rcnt[e], 1);
        ridxP[e * NREF + p] = i | (q << 16);     // ref id | compact pos
    } else if (i < NCOMB) {
        int t = i - NREF;
        int e = lt[t] - 1;
        int q = atomicAdd(&cnt[e], 1);
        comb[e * NCOMB + q] = NREF + t;
        post[t] = q;                              // train compact pos
    }
}

// ---------------------------------------------------------------------------
// Fused prep: [0,1536) W1 transpose+split; [1536,4992) x gather+split;
// [4992,4996) zero hfin.
#define PREP_TR1  1536
#define PREP_GAT  (PREP_TR1 + ESTR/4*NE)
#define PREP_ZERO (PREP_GAT + 4)
__global__ __launch_bounds__(256) void k_prep(
    const float* __restrict__ W1,
    const float* __restrict__ xr, const float* __restrict__ xt,
    const int* __restrict__ cnt, const int* __restrict__ comb,
    short* __restrict__ W1Th, short* __restrict__ W1Tl,
    short* __restrict__ XgH, short* __restrict__ XgL,
    float* __restrict__ hfinC) {
    __shared__ float s[32][33];
    int b = blockIdx.x;
    if (b < PREP_TR1) {
        int e = b / 384, r = b % 384;
        int n0 = (r & 31) * 32, k0 = (r >> 5) * 32;
        int tx = threadIdx.x & 31, ty = threadIdx.x >> 5;
        const float* src = W1 + (size_t)e * DIN * HID;
#pragma unroll
        for (int i = 0; i < 32; i += 8)
            s[ty + i][tx] = src[(size_t)(k0 + ty + i) * HID + n0 + tx];
        __syncthreads();
#pragma unroll
        for (int i = 0; i < 32; i += 8) {
            float v = s[tx][ty + i];
            short hb = f2bf(v);
            short lb = f2bf(v - bf2f(hb));
            size_t o = ((size_t)e * HID + n0 + ty + i) * DIN + k0 + tx;
            W1Th[o] = hb;
            W1Tl[o] = lb;
        }
    } else if (b < PREP_GAT) {
        int b2 = b - PREP_TR1;
        int e = b2 / (ESTR / 4);
        int m = (b2 % (ESTR / 4)) * 4 + (threadIdx.x >> 6);
        int lane = threadIdx.x & 63;
        size_t dst = ((size_t)e * ESTR + m) * DIN;
        if (m < cnt[e]) {
            int g = comb[e * NCOMB + m];
            const float* src = (g < NREF) ? (xr + (size_t)g * DIN)
                                          : (xt + (size_t)(g - NREF) * DIN);
#pragma unroll
            for (int c = lane * 2, it = 0; it < 3; c += 128, ++it) {
                float2 v = *(const float2*)(src + c);
                short2 h, l;
                h.x = f2bf(v.x); l.x = f2bf(v.x - bf2f(h.x));
                h.y = f2bf(v.y); l.y = f2bf(v.y - bf2f(h.y));
                *(short2*)(XgH + dst + c) = h;
                *(short2*)(XgL + dst + c) = l;
            }
        } else {
#pragma unroll
            for (int c = lane * 2, it = 0; it < 3; c += 128, ++it) {
                *(short2*)(XgH + dst + c) = short2{0, 0};
                *(short2*)(XgL + dst + c) = short2{0, 0};
            }
        }
    } else {
        int idx = (b - PREP_GAT) * 1024 + threadIdx.x;
        if (idx * 4 < NE * ESTR) {
            f32x4 z = {0.f, 0.f, 0.f, 0.f};
            *(f32x4*)(hfinC + idx * 4) = z;
        }
    }
}

// W2 transpose + hi/lo split with permuted K. pi(k)=(k&~63)|((k&15)<<2)|((k>>4)&3)
__global__ __launch_bounds__(256) void k_tr2(const float* __restrict__ W,
                                             short* __restrict__ Th,
                                             short* __restrict__ Tl) {
    int e = blockIdx.z;
    __shared__ float s[32][33];
    int tx = threadIdx.x & 31, ty = threadIdx.x >> 5;
    int k0 = blockIdx.y * 32, n0 = blockIdx.x * 32;
    const float* src = W + (size_t)e * HID * HID;
#pragma unroll
    for (int i = 0; i < 32; i += 8)
        s[ty + i][tx] = src[(size_t)(k0 + ty + i) * HID + n0 + tx];
    __syncthreads();
    int k = k0 + tx;
    int kk = (k & ~63) | ((k & 15) << 2) | ((k >> 4) & 3);
#pragma unroll
    for (int i = 0; i < 32; i += 8) {
        float v = s[tx][ty + i];
        short hb = f2bf(v);
        short lb = f2bf(v - bf2f(hb));
        size_t o = ((size_t)e * HID + n0 + ty + i) * HID + kk;
        Th[o] = hb;
        Tl[o] = lb;
    }
}

// ---------------------------------------------------------------------------
// Shared fragment-read helper (per-slot layout: Ah@0, Al@8K, Bh@16K, Bl@24K;
// 64B rows, XOR-swizzled 16B chunks)
#define READ_FRAGS(slotp)                                                     \
    bf16x8 ah[4], al[4], bh[4], bl[4];                                        \
    _Pragma("unroll")                                                         \
    for (int m = 0; m < 4; m++) {                                             \
        int row = wr * 64 + m * 16 + (lane & 15);                             \
        int off = row * 64 + ((((lane >> 4) ^ ((row >> 1) & 3))) << 4);       \
        ah[m] = *(const bf16x8*)((slotp) + off);                              \
        al[m] = *(const bf16x8*)((slotp) + 8192 + off);                       \
    }                                                                         \
    _Pragma("unroll")                                                         \
    for (int n = 0; n < 4; n++) {                                             \
        int row = wc * 64 + n * 16 + (lane & 15);                             \
        int off = row * 64 + ((((lane >> 4) ^ ((row >> 1) & 3))) << 4);       \
        bh[n] = *(const bf16x8*)((slotp) + 16384 + off);                      \
        bl[n] = *(const bf16x8*)((slotp) + 24576 + off);                      \
    }

#define DO_MFMA()                                                             \
    __builtin_amdgcn_s_setprio(1);                                            \
    _Pragma("unroll")                                                         \
    for (int m = 0; m < 4; m++)                                               \
        _Pragma("unroll")                                                     \
        for (int n = 0; n < 4; n++) {                                         \
            acc[m][n] = __builtin_amdgcn_mfma_f32_16x16x32_bf16(ah[m], bh[n], acc[m][n], 0, 0, 0); \
            acc[m][n] = __builtin_amdgcn_mfma_f32_16x16x32_bf16(al[m], bh[n], acc[m][n], 0, 0, 0); \
            acc[m][n] = __builtin_amdgcn_mfma_f32_16x16x32_bf16(ah[m], bl[n], acc[m][n], 0, 0, 0); \
        }                                                                     \
    __builtin_amdgcn_s_setprio(0);

// Pipelined loop: 2-slot double buffer (64KB), STAGE(t+1) issued BEFORE
// compute(t) so vmcnt(0) at iter top waits a load issued one full compute
// phase earlier. One s_barrier per iter.
#define PIPE_LOOP(NT, STAGE)                                                  \
    STAGE(0, 0);                                                              \
    for (int kt = 0; kt < (NT); ++kt) {                                       \
        __builtin_amdgcn_sched_barrier(0);                                    \
        asm volatile("s_waitcnt vmcnt(0)" ::: "memory");                      \
        __builtin_amdgcn_s_barrier();                                         \
        __builtin_amdgcn_sched_barrier(0);                                    \
        if (kt + 1 < (NT)) STAGE(kt + 1, (kt + 1) & 1);                       \
        char* slotp = smem + (kt & 1) * 32768;                                \
        READ_FRAGS(slotp)                                                     \
        DO_MFMA()                                                             \
    }

// ---------------------------------------------------------------------------
// Layer 1: H1C = celu(Xg @ W1 + b1). 128x128 tile, BK=32, 4 waves.
__global__ __launch_bounds__(256) void k_l1(
    const short* __restrict__ XgH, const short* __restrict__ XgL,
    const short* __restrict__ W1Th, const short* __restrict__ W1Tl,
    const float* __restrict__ b1, const int* __restrict__ cnt,
    short* __restrict__ H1h, short* __restrict__ H1l) {
    int bid = blockIdx.x;
    int n0 = (bid & 7) * 128;
    int rest = bid >> 3;
    int e = rest / MT;
    int count = cnt[e];
    int m0 = (rest % MT) * 128;
    if (m0 >= count) return;

    extern __shared__ __align__(16) char smem[];   // 2 * 32768
    int t = threadIdx.x, w = t >> 6, lane = t & 63;
    int wr = w >> 1, wc = w & 1;

    int srow = t >> 2, sx = t & 3, fB = (srow >> 1) & 3;
    size_t aoff0 = ((size_t)e * ESTR + m0 + srow) * DIN + (sx ^ fB) * 8;
    size_t aoff1 = aoff0 + (size_t)64 * DIN;
    size_t boff0 = ((size_t)e * HID + n0 + srow) * DIN + (sx ^ fB) * 8;
    size_t boff1 = boff0 + (size_t)64 * DIN;
    char* ldsW = smem + w * 1024;   // wave-uniform base; HW adds lane*16

#define STAGE1(T, SL) do { int kk = (T) * 32; char* Ld = ldsW + (SL) * 32768; \
        gload16(XgH  + aoff0 + kk, Ld + 0);     gload16(XgH  + aoff1 + kk, Ld + 4096);  \
        gload16(XgL  + aoff0 + kk, Ld + 8192);  gload16(XgL  + aoff1 + kk, Ld + 12288); \
        gload16(W1Th + boff0 + kk, Ld + 16384); gload16(W1Th + boff1 + kk, Ld + 20480); \
        gload16(W1Tl + boff0 + kk, Ld + 24576); gload16(W1Tl + boff1 + kk, Ld + 28672); } while (0)

    f32x4 acc[4][4] = {};
    PIPE_LOOP(DIN / 32, STAGE1)
#undef STAGE1

    // epilogue: bias+celu, split, permuted short4 store
    int q = lane & 15;
    float bb[4];
#pragma unroll
    for (int n = 0; n < 4; n++) bb[n] = b1[e * HID + n0 + wc * 64 + n * 16 + q];
#pragma unroll
    for (int m = 0; m < 4; m++) {
        int rbase = m0 + wr * 64 + m * 16 + (lane >> 4) * 4;
#pragma unroll
        for (int r = 0; r < 4; r++) {
            int row = rbase + r;
            if (row < count) {
                s16x4 hv, lv;
#pragma unroll
                for (int n = 0; n < 4; n++) {
                    float v = celu1(acc[m][n][r] + bb[n]);
                    hv[n] = f2bf(v);
                    lv[n] = f2bf(v - bf2f(hv[n]));
                }
                size_t o = ((size_t)e * ESTR + row) * HID + n0 + wc * 64 + q * 4;
                *(s16x4*)(H1h + o) = hv;
                *(s16x4*)(H1l + o) = lv;
            }
        }
    }
}

// ---------------------------------------------------------------------------
// Layers 2+3 fused. mtBase/mtN select an M-slice (launched twice for
// profiling visibility; disjoint output rows).
__global__ __launch_bounds__(256) void k_l23(
    const short* __restrict__ H1h, const short* __restrict__ H1l,
    const short* __restrict__ W2Th, const short* __restrict__ W2Tl,
    const float* __restrict__ b2, const float* __restrict__ W3,
    const int* __restrict__ cnt, float* __restrict__ hfinC,
    int mtBase, int mtN) {
    int bid = blockIdx.x;
    int n0 = (bid & 7) * 128;
    int rest = bid >> 3;
    int e = rest / mtN;
    int count = cnt[e];
    int m0 = (mtBase + rest % mtN) * 128;
    if (m0 >= count) return;

    extern __shared__ __align__(16) char smem[];   // 2 * 32768
    int t = threadIdx.x, w = t >> 6, lane = t & 63;
    int wr = w >> 1, wc = w & 1;

    int srow = t >> 2, sx = t & 3, f0 = (srow >> 1) & 3;
    size_t aoff0 = ((size_t)e * ESTR + m0 + srow) * HID + (sx ^ f0) * 8;
    size_t aoff1 = aoff0 + (size_t)64 * HID;
    size_t boff0 = ((size_t)e * HID + n0 + srow) * HID + (sx ^ f0) * 8;
    size_t boff1 = boff0 + (size_t)64 * HID;
    char* ldsW = smem + w * 1024;

#define STAGE23(T, SL) do { int kk = (T) * 32; char* Ld = ldsW + (SL) * 32768; \
        gload16(H1h  + aoff0 + kk, Ld + 0);     gload16(H1h  + aoff1 + kk, Ld + 4096);  \
        gload16(H1l  + aoff0 + kk, Ld + 8192);  gload16(H1l  + aoff1 + kk, Ld + 12288); \
        gload16(W2Th + boff0 + kk, Ld + 16384); gload16(W2Th + boff1 + kk, Ld + 20480); \
        gload16(W2Tl + boff0 + kk, Ld + 24576); gload16(W2Tl + boff1 + kk, Ld + 28672); } while (0)

    f32x4 acc[4][4] = {};
    PIPE_LOOP(HID / 32, STAGE23)
#undef STAGE23

    // epilogue: celu + W3-weight, reduce over 128 cols of this tile
    float s[4][4] = {};
#pragma unroll
    for (int n = 0; n < 4; n++) {
        int col = n0 + wc * 64 + n * 16 + (lane & 15);
        float bbv = b2[e * HID + col];
        float w3 = W3[e * HID + col];
#pragma unroll
        for (int m = 0; m < 4; m++)
#pragma unroll
            for (int r = 0; r < 4; r++)
                s[m][r] += celu1(acc[m][n][r] + bbv) * w3;
    }
#pragma unroll
    for (int m = 0; m < 4; m++)
#pragma unroll
        for (int r = 0; r < 4; r++) {
#pragma unroll
            for (int off = 8; off > 0; off >>= 1)
                s[m][r] += __shfl_xor(s[m][r], off, 64);
        }
    if ((lane & 15) == 0) {
#pragma unroll
        for (int m = 0; m < 4; m++) {
            int rbase = m0 + wr * 64 + m * 16 + (lane >> 4) * 4;
#pragma unroll
            for (int r = 0; r < 4; r++)
                if (rbase + r < count)
                    atomicAdd(&hfinC[e * ESTR + rbase + r], s[m][r]);
        }
    }
}

// ---------------------------------------------------------------------------
__global__ __launch_bounds__(256) void k_out(
    const int* __restrict__ lt, const float* __restrict__ yref,
    const float* __restrict__ alpha, const int* __restrict__ rcnt,
    const int* __restrict__ ridxP, const int* __restrict__ post,
    const float* __restrict__ hfinC, float* __restrict__ out) {
    int t = blockIdx.x * 4 + (threadIdx.x >> 6);
    int lane = threadIdx.x & 63;
    if (t >= NTR) return;
    int lab = lt[t];
    int e = lab - 1;
    float ht = hfinC[e * ESTR + post[t]];
    float a = alpha[e];
    int n = rcnt[e];
    const int* lst = ridxP + e * NREF;
    float num = 0.f, den = 0.f;
    for (int i = lane; i < n; i += 64) {
        int pk = lst[i];
        int r = pk & 0xFFFF;
        int pq = pk >> 16;
        float d = fabsf(ht - hfinC[e * ESTR + pq]);
        float p = expf(-a * d);
        num += p * yref[r];
        den += p;
    }
#pragma unroll
    for (int o = 32; o > 0; o >>= 1) {
        num += __shfl_down(num, o, 64);
        den += __shfl_down(den, o, 64);
    }
    if (lane == 0) {
        out[t] = (float)lab;
        out[NTR + t] = num / den;
    }
}

extern "C" void kernel_launch(void* const* d_in, const int* in_sizes, int n_in,
                              void* d_out, int out_size, void* d_ws, size_t ws_size,
                              hipStream_t stream) {
    const float* xr    = (const float*)d_in[0];
    const float* yref  = (const float*)d_in[1];
    const int*   lr    = (const int*)  d_in[2];
    const float* xt    = (const float*)d_in[3];
    const int*   lt    = (const int*)  d_in[4];
    const float* W1    = (const float*)d_in[5];
    const float* b1    = (const float*)d_in[6];
    const float* W2    = (const float*)d_in[7];
    const float* b2    = (const float*)d_in[8];
    const float* W3    = (const float*)d_in[9];
    // d_in[10] = b3 (cancels in |ht-hr|), d_in[11] = alpha
    const float* alpha = (const float*)d_in[11];

    // allow 64KB dynamic LDS (capture-safe host-side attribute, idempotent)
    hipFuncSetAttribute((const void*)k_l1,
                        hipFuncAttributeMaxDynamicSharedMemorySize, 2 * 32768);
    hipFuncSetAttribute((const void*)k_l23,
                        hipFuncAttributeMaxDynamicSharedMemorySize, 2 * 32768);

    char* ws = (char*)d_ws;
    int*   cnt   = (int*)(ws + WS_CNT);
    int*   rcnt  = (int*)(ws + WS_RCNT);
    int*   post  = (int*)(ws + WS_POST);
    int*   ridxP = (int*)(ws + WS_RIDX);
    int*   comb  = (int*)(ws + WS_COMB);
    short* W1Th  = (short*)(ws + WS_W1TH);
    short* W1Tl  = (short*)(ws + WS_W1TL);
    short* XgH   = (short*)(ws + WS_XGH);
    short* XgL   = (short*)(ws + WS_XGL);
    short* W2Th  = (short*)(ws + WS_W2TH);   // aliases XgH (Xg dead after k_l1)
    short* W2Tl  = (short*)(ws + WS_W2TL);   // aliases XgL
    short* H1h   = (short*)(ws + WS_H1H);
    short* H1l   = (short*)(ws + WS_H1L);
    float* hfinC = (float*)(ws + WS_HFIN);
    float* out   = (float*)d_out;

    hipMemsetAsync(ws, 0, 32, stream);                      // cnt + rcnt

    k_compact<<<NCOMB / 256, 256, 0, stream>>>(lr, lt, cnt, rcnt, comb, ridxP, post);

    k_prep<<<PREP_ZERO, 256, 0, stream>>>(W1, xr, xt, cnt, comb,
                                          W1Th, W1Tl, XgH, XgL, hfinC);

    k_l1<<<8 * MT * NE, 256, 2 * 32768, stream>>>(XgH, XgL, W1Th, W1Tl, b1, cnt,
                                                  H1h, H1l);

    // W2 transpose AFTER k_l1 (it overwrites the Xg region)
    k_tr2<<<dim3(HID / 32, HID / 32, NE), 256, 0, stream>>>(W2, W2Th, W2Tl);

    // l23 in two M-slices (disjoint rows; split for profiling visibility)
    k_l23<<<8 * 14 * NE, 256, 2 * 32768, stream>>>(H1h, H1l, W2Th, W2Tl, b2, W3,
                                                   cnt, hfinC, 0, 14);
    k_l23<<<8 * 13 * NE, 256, 2 * 32768, stream>>>(H1h, H1l, W2Th, W2Tl, b2, W3,
                                                   cnt, hfinC, 14, 13);

    k_out<<<NTR / 4, 256, 0, stream>>>(lt, yref, alpha, rcnt, ridxP, post, hfinC, out);
}

// Round 8
// 292.319 us; speedup vs baseline: 1.4690x; 1.2713x over previous
//
#include <hip/hip_runtime.h>
#include <hip/hip_bf16.h>

#define NREF  4096
#define NTR   8192
#define NCOMB 12288
#define DIN   384
#define HID   1024
#define NE    4
#define ESTR  3456   // per-element compact row stride (count~3072, +pad)
#define MT    (ESTR / 128)   // 27 m-tiles

typedef __attribute__((ext_vector_type(8))) short bf16x8;
typedef __attribute__((ext_vector_type(4))) short s16x4;
typedef __attribute__((ext_vector_type(4))) float f32x4;

// ---------------------------------------------------------------------------
// ws layout (bytes)
#define WS_CNT    0
#define WS_RCNT   16
#define WS_POST   256                                   // NTR*4 = 32768
#define WS_RIDX   (WS_POST + NTR*4)                     // NE*NREF*4 = 65536
#define WS_COMB   (WS_RIDX + NE*NREF*4)                 // NE*NCOMB*4 = 196608
#define WS_W1TH   524288
#define WS_W1TL   (WS_W1TH + NE*DIN*HID*2)              // +3145728
#define WS_XGH    (WS_W1TL + NE*DIN*HID*2)              // 6815744
#define WS_XGL    (WS_XGH + NE*ESTR*DIN*2)              // +10616832
#define WS_W2TH   WS_XGH                                 // alias: Xg dead after k_l1
#define WS_W2TL   WS_XGL
#define WS_H1H    (WS_XGL + NE*ESTR*DIN*2)              // 28049408
#define WS_H1L    (WS_H1H + (size_t)NE*ESTR*HID*2)      // +28311552
#define WS_HFIN   (WS_H1L + (size_t)NE*ESTR*HID*2)      // 84672512 (+55296)
// total ~84.8 MB
// ---------------------------------------------------------------------------

__device__ __forceinline__ short f2bf(float f) {
    unsigned u = __builtin_bit_cast(unsigned, f);
    unsigned r = (u + 0x7FFF + ((u >> 16) & 1)) >> 16;   // RNE
    return (short)r;
}
__device__ __forceinline__ float bf2f(short s) {
    unsigned u = ((unsigned)(unsigned short)s) << 16;
    return __builtin_bit_cast(float, u);
}
__device__ __forceinline__ void gload16(const void* g, void* l) {
    __builtin_amdgcn_global_load_lds(
        (const __attribute__((address_space(1))) void*)g,
        (__attribute__((address_space(3))) void*)l, 16, 0, 0);
}
__device__ __forceinline__ float celu1(float v) {
    return v > 0.f ? v : (expf(v) - 1.f);
}

// ---------------------------------------------------------------------------
// Atomic-free compaction: single 1024-thread workgroup, 12 items/thread,
// two-level exclusive prefix scan per element bucket. Deterministic order;
// refs precede trains so a ref's compact pos == its ref-list pos.
__global__ __launch_bounds__(1024) void k_compact(
    const int* __restrict__ lr, const int* __restrict__ lt,
    int* cnt, int* rcnt, int* comb, int* ridxP, int* post) {
    int t = threadIdx.x;
    int wid = t >> 6, lane = t & 63;
    int base = t * 12;

    int lab[12];
    int c0 = 0, c1 = 0, c2 = 0, c3 = 0;      // all-items counts
    int r0 = 0, r1 = 0, r2 = 0, r3 = 0;      // ref-only counts
#pragma unroll
    for (int j = 0; j < 12; j++) {
        int i = base + j;
        int l = (i < NREF) ? lr[i] : lt[i - NREF];
        lab[j] = l;
        c0 += (l == 1); c1 += (l == 2); c2 += (l == 3); c3 += (l == 4);
        if (i < NREF) {
            r0 += (l == 1); r1 += (l == 2); r2 += (l == 3); r3 += (l == 4);
        }
    }

    // wave-level inclusive scan of per-thread counts
    int v0 = c0, v1 = c1, v2 = c2, v3 = c3;
#pragma unroll
    for (int off = 1; off < 64; off <<= 1) {
        int u0 = __shfl_up(v0, off, 64), u1 = __shfl_up(v1, off, 64);
        int u2 = __shfl_up(v2, off, 64), u3 = __shfl_up(v3, off, 64);
        if (lane >= off) { v0 += u0; v1 += u1; v2 += u2; v3 += u3; }
    }
    // ref-only wave totals (reduction)
    int s0 = r0, s1 = r1, s2 = r2, s3 = r3;
#pragma unroll
    for (int off = 32; off > 0; off >>= 1) {
        s0 += __shfl_xor(s0, off, 64); s1 += __shfl_xor(s1, off, 64);
        s2 += __shfl_xor(s2, off, 64); s3 += __shfl_xor(s3, off, 64);
    }

    __shared__ int wtot[16][4], woff[16][4], rtot[16][4];
    if (lane == 63) {
        wtot[wid][0] = v0; wtot[wid][1] = v1; wtot[wid][2] = v2; wtot[wid][3] = v3;
    }
    if (lane == 0) {
        rtot[wid][0] = s0; rtot[wid][1] = s1; rtot[wid][2] = s2; rtot[wid][3] = s3;
    }
    __syncthreads();
    if (t == 0) {
        int a0 = 0, a1 = 0, a2 = 0, a3 = 0, b0 = 0, b1 = 0, b2 = 0, b3 = 0;
#pragma unroll
        for (int w = 0; w < 16; w++) {
            woff[w][0] = a0; woff[w][1] = a1; woff[w][2] = a2; woff[w][3] = a3;
            a0 += wtot[w][0]; a1 += wtot[w][1]; a2 += wtot[w][2]; a3 += wtot[w][3];
            b0 += rtot[w][0]; b1 += rtot[w][1]; b2 += rtot[w][2]; b3 += rtot[w][3];
        }
        cnt[0] = a0; cnt[1] = a1; cnt[2] = a2; cnt[3] = a3;
        rcnt[0] = b0; rcnt[1] = b1; rcnt[2] = b2; rcnt[3] = b3;
    }
    __syncthreads();

    // per-thread exclusive offsets within each bucket
    int q0 = v0 - c0 + woff[wid][0];
    int q1 = v1 - c1 + woff[wid][1];
    int q2 = v2 - c2 + woff[wid][2];
    int q3 = v3 - c3 + woff[wid][3];

#pragma unroll
    for (int j = 0; j < 12; j++) {
        int i = base + j;
        int l = lab[j];
        int p = (l == 1) ? q0 : (l == 2) ? q1 : (l == 3) ? q2 : q3;
        q0 += (l == 1); q1 += (l == 2); q2 += (l == 3); q3 += (l == 4);
        int e = l - 1;
        comb[e * NCOMB + p] = i;
        if (i < NREF) ridxP[e * NREF + p] = i | (p << 16);   // ref id | compact pos
        else          post[i - NREF] = p;                     // train compact pos
    }
}

// ---------------------------------------------------------------------------
// Fused prep: [0,1536) W1 transpose+split; [1536,4992) x gather+split;
// [4992,4996) zero hfin.
#define PREP_TR1  1536
#define PREP_GAT  (PREP_TR1 + ESTR/4*NE)
#define PREP_ZERO (PREP_GAT + 4)
__global__ __launch_bounds__(256) void k_prep(
    const float* __restrict__ W1,
    const float* __restrict__ xr, const float* __restrict__ xt,
    const int* __restrict__ cnt, const int* __restrict__ comb,
    short* __restrict__ W1Th, short* __restrict__ W1Tl,
    short* __restrict__ XgH, short* __restrict__ XgL,
    float* __restrict__ hfinC) {
    __shared__ float s[32][33];
    int b = blockIdx.x;
    if (b < PREP_TR1) {
        int e = b / 384, r = b % 384;
        int n0 = (r & 31) * 32, k0 = (r >> 5) * 32;
        int tx = threadIdx.x & 31, ty = threadIdx.x >> 5;
        const float* src = W1 + (size_t)e * DIN * HID;
#pragma unroll
        for (int i = 0; i < 32; i += 8)
            s[ty + i][tx] = src[(size_t)(k0 + ty + i) * HID + n0 + tx];
        __syncthreads();
#pragma unroll
        for (int i = 0; i < 32; i += 8) {
            float v = s[tx][ty + i];
            short hb = f2bf(v);
            short lb = f2bf(v - bf2f(hb));
            size_t o = ((size_t)e * HID + n0 + ty + i) * DIN + k0 + tx;
            W1Th[o] = hb;
            W1Tl[o] = lb;
        }
    } else if (b < PREP_GAT) {
        int b2 = b - PREP_TR1;
        int e = b2 / (ESTR / 4);
        int m = (b2 % (ESTR / 4)) * 4 + (threadIdx.x >> 6);
        int lane = threadIdx.x & 63;
        size_t dst = ((size_t)e * ESTR + m) * DIN;
        if (m < cnt[e]) {
            int g = comb[e * NCOMB + m];
            const float* src = (g < NREF) ? (xr + (size_t)g * DIN)
                                          : (xt + (size_t)(g - NREF) * DIN);
#pragma unroll
            for (int c = lane * 2, it = 0; it < 3; c += 128, ++it) {
                float2 v = *(const float2*)(src + c);
                short2 h, l;
                h.x = f2bf(v.x); l.x = f2bf(v.x - bf2f(h.x));
                h.y = f2bf(v.y); l.y = f2bf(v.y - bf2f(h.y));
                *(short2*)(XgH + dst + c) = h;
                *(short2*)(XgL + dst + c) = l;
            }
        } else {
#pragma unroll
            for (int c = lane * 2, it = 0; it < 3; c += 128, ++it) {
                *(short2*)(XgH + dst + c) = short2{0, 0};
                *(short2*)(XgL + dst + c) = short2{0, 0};
            }
        }
    } else {
        int idx = (b - PREP_GAT) * 1024 + threadIdx.x;
        if (idx * 4 < NE * ESTR) {
            f32x4 z = {0.f, 0.f, 0.f, 0.f};
            *(f32x4*)(hfinC + idx * 4) = z;
        }
    }
}

// W2 transpose + hi/lo split with permuted K. pi(k)=(k&~63)|((k&15)<<2)|((k>>4)&3)
__global__ __launch_bounds__(256) void k_tr2(const float* __restrict__ W,
                                             short* __restrict__ Th,
                                             short* __restrict__ Tl) {
    int e = blockIdx.z;
    __shared__ float s[32][33];
    int tx = threadIdx.x & 31, ty = threadIdx.x >> 5;
    int k0 = blockIdx.y * 32, n0 = blockIdx.x * 32;
    const float* src = W + (size_t)e * HID * HID;
#pragma unroll
    for (int i = 0; i < 32; i += 8)
        s[ty + i][tx] = src[(size_t)(k0 + ty + i) * HID + n0 + tx];
    __syncthreads();
    int k = k0 + tx;
    int kk = (k & ~63) | ((k & 15) << 2) | ((k >> 4) & 3);
#pragma unroll
    for (int i = 0; i < 32; i += 8) {
        float v = s[tx][ty + i];
        short hb = f2bf(v);
        short lb = f2bf(v - bf2f(hb));
        size_t o = ((size_t)e * HID + n0 + ty + i) * HID + kk;
        Th[o] = hb;
        Tl[o] = lb;
    }
}

// ---------------------------------------------------------------------------
// Shared fragment-read helper (per-slot layout: Ah@0, Al@8K, Bh@16K, Bl@24K;
// 64B rows, XOR-swizzled 16B chunks)
#define READ_FRAGS(slotp)                                                     \
    bf16x8 ah[4], al[4], bh[4], bl[4];                                        \
    _Pragma("unroll")                                                         \
    for (int m = 0; m < 4; m++) {                                             \
        int row = wr * 64 + m * 16 + (lane & 15);                             \
        int off = row * 64 + ((((lane >> 4) ^ ((row >> 1) & 3))) << 4);       \
        ah[m] = *(const bf16x8*)((slotp) + off);                              \
        al[m] = *(const bf16x8*)((slotp) + 8192 + off);                       \
    }                                                                         \
    _Pragma("unroll")                                                         \
    for (int n = 0; n < 4; n++) {                                             \
        int row = wc * 64 + n * 16 + (lane & 15);                             \
        int off = row * 64 + ((((lane >> 4) ^ ((row >> 1) & 3))) << 4);       \
        bh[n] = *(const bf16x8*)((slotp) + 16384 + off);                      \
        bl[n] = *(const bf16x8*)((slotp) + 24576 + off);                      \
    }

#define DO_MFMA()                                                             \
    __builtin_amdgcn_s_setprio(1);                                            \
    _Pragma("unroll")                                                         \
    for (int m = 0; m < 4; m++)                                               \
        _Pragma("unroll")                                                     \
        for (int n = 0; n < 4; n++) {                                         \
            acc[m][n] = __builtin_amdgcn_mfma_f32_16x16x32_bf16(ah[m], bh[n], acc[m][n], 0, 0, 0); \
            acc[m][n] = __builtin_amdgcn_mfma_f32_16x16x32_bf16(al[m], bh[n], acc[m][n], 0, 0, 0); \
            acc[m][n] = __builtin_amdgcn_mfma_f32_16x16x32_bf16(ah[m], bl[n], acc[m][n], 0, 0, 0); \
        }                                                                     \
    __builtin_amdgcn_s_setprio(0);

// Pipelined loop: 2-slot double buffer (64KB), STAGE(t+1) issued BEFORE
// compute(t) so vmcnt(0) at iter top waits a load issued one full compute
// phase earlier. One s_barrier per iter.
#define PIPE_LOOP(NT, STAGE)                                                  \
    STAGE(0, 0);                                                              \
    for (int kt = 0; kt < (NT); ++kt) {                                       \
        __builtin_amdgcn_sched_barrier(0);                                    \
        asm volatile("s_waitcnt vmcnt(0)" ::: "memory");                      \
        __builtin_amdgcn_s_barrier();                                         \
        __builtin_amdgcn_sched_barrier(0);                                    \
        if (kt + 1 < (NT)) STAGE(kt + 1, (kt + 1) & 1);                       \
        char* slotp = smem + (kt & 1) * 32768;                                \
        READ_FRAGS(slotp)                                                     \
        DO_MFMA()                                                             \
    }

// ---------------------------------------------------------------------------
// Layer 1: H1C = celu(Xg @ W1 + b1). 128x128 tile, BK=32, 4 waves.
__global__ __launch_bounds__(256) void k_l1(
    const short* __restrict__ XgH, const short* __restrict__ XgL,
    const short* __restrict__ W1Th, const short* __restrict__ W1Tl,
    const float* __restrict__ b1, const int* __restrict__ cnt,
    short* __restrict__ H1h, short* __restrict__ H1l) {
    int bid = blockIdx.x;
    int n0 = (bid & 7) * 128;
    int rest = bid >> 3;
    int e = rest / MT;
    int count = cnt[e];
    int m0 = (rest % MT) * 128;
    if (m0 >= count) return;

    extern __shared__ __align__(16) char smem[];   // 2 * 32768
    int t = threadIdx.x, w = t >> 6, lane = t & 63;
    int wr = w >> 1, wc = w & 1;

    int srow = t >> 2, sx = t & 3, fB = (srow >> 1) & 3;
    size_t aoff0 = ((size_t)e * ESTR + m0 + srow) * DIN + (sx ^ fB) * 8;
    size_t aoff1 = aoff0 + (size_t)64 * DIN;
    size_t boff0 = ((size_t)e * HID + n0 + srow) * DIN + (sx ^ fB) * 8;
    size_t boff1 = boff0 + (size_t)64 * DIN;
    char* ldsW = smem + w * 1024;   // wave-uniform base; HW adds lane*16

#define STAGE1(T, SL) do { int kk = (T) * 32; char* Ld = ldsW + (SL) * 32768; \
        gload16(XgH  + aoff0 + kk, Ld + 0);     gload16(XgH  + aoff1 + kk, Ld + 4096);  \
        gload16(XgL  + aoff0 + kk, Ld + 8192);  gload16(XgL  + aoff1 + kk, Ld + 12288); \
        gload16(W1Th + boff0 + kk, Ld + 16384); gload16(W1Th + boff1 + kk, Ld + 20480); \
        gload16(W1Tl + boff0 + kk, Ld + 24576); gload16(W1Tl + boff1 + kk, Ld + 28672); } while (0)

    f32x4 acc[4][4] = {};
    PIPE_LOOP(DIN / 32, STAGE1)
#undef STAGE1

    // epilogue: bias+celu, split, permuted short4 store
    int q = lane & 15;
    float bb[4];
#pragma unroll
    for (int n = 0; n < 4; n++) bb[n] = b1[e * HID + n0 + wc * 64 + n * 16 + q];
#pragma unroll
    for (int m = 0; m < 4; m++) {
        int rbase = m0 + wr * 64 + m * 16 + (lane >> 4) * 4;
#pragma unroll
        for (int r = 0; r < 4; r++) {
            int row = rbase + r;
            if (row < count) {
                s16x4 hv, lv;
#pragma unroll
                for (int n = 0; n < 4; n++) {
                    float v = celu1(acc[m][n][r] + bb[n]);
                    hv[n] = f2bf(v);
                    lv[n] = f2bf(v - bf2f(hv[n]));
                }
                size_t o = ((size_t)e * ESTR + row) * HID + n0 + wc * 64 + q * 4;
                *(s16x4*)(H1h + o) = hv;
                *(s16x4*)(H1l + o) = lv;
            }
        }
    }
}

// ---------------------------------------------------------------------------
// Layers 2+3 fused. mtBase/mtN select an M-slice (launched twice for
// profiling visibility; disjoint output rows).
__global__ __launch_bounds__(256) void k_l23(
    const short* __restrict__ H1h, const short* __restrict__ H1l,
    const short* __restrict__ W2Th, const short* __restrict__ W2Tl,
    const float* __restrict__ b2, const float* __restrict__ W3,
    const int* __restrict__ cnt, float* __restrict__ hfinC,
    int mtBase, int mtN) {
    int bid = blockIdx.x;
    int n0 = (bid & 7) * 128;
    int rest = bid >> 3;
    int e = rest / mtN;
    int count = cnt[e];
    int m0 = (mtBase + rest % mtN) * 128;
    if (m0 >= count) return;

    extern __shared__ __align__(16) char smem[];   // 2 * 32768
    int t = threadIdx.x, w = t >> 6, lane = t & 63;
    int wr = w >> 1, wc = w & 1;

    int srow = t >> 2, sx = t & 3, f0 = (srow >> 1) & 3;
    size_t aoff0 = ((size_t)e * ESTR + m0 + srow) * HID + (sx ^ f0) * 8;
    size_t aoff1 = aoff0 + (size_t)64 * HID;
    size_t boff0 = ((size_t)e * HID + n0 + srow) * HID + (sx ^ f0) * 8;
    size_t boff1 = boff0 + (size_t)64 * HID;
    char* ldsW = smem + w * 1024;

#define STAGE23(T, SL) do { int kk = (T) * 32; char* Ld = ldsW + (SL) * 32768; \
        gload16(H1h  + aoff0 + kk, Ld + 0);     gload16(H1h  + aoff1 + kk, Ld + 4096);  \
        gload16(H1l  + aoff0 + kk, Ld + 8192);  gload16(H1l  + aoff1 + kk, Ld + 12288); \
        gload16(W2Th + boff0 + kk, Ld + 16384); gload16(W2Th + boff1 + kk, Ld + 20480); \
        gload16(W2Tl + boff0 + kk, Ld + 24576); gload16(W2Tl + boff1 + kk, Ld + 28672); } while (0)

    f32x4 acc[4][4] = {};
    PIPE_LOOP(HID / 32, STAGE23)
#undef STAGE23

    // epilogue: celu + W3-weight, reduce over 128 cols of this tile
    float s[4][4] = {};
#pragma unroll
    for (int n = 0; n < 4; n++) {
        int col = n0 + wc * 64 + n * 16 + (lane & 15);
        float bbv = b2[e * HID + col];
        float w3 = W3[e * HID + col];
#pragma unroll
        for (int m = 0; m < 4; m++)
#pragma unroll
            for (int r = 0; r < 4; r++)
                s[m][r] += celu1(acc[m][n][r] + bbv) * w3;
    }
#pragma unroll
    for (int m = 0; m < 4; m++)
#pragma unroll
        for (int r = 0; r < 4; r++) {
#pragma unroll
            for (int off = 8; off > 0; off >>= 1)
                s[m][r] += __shfl_xor(s[m][r], off, 64);
        }
    if ((lane & 15) == 0) {
#pragma unroll
        for (int m = 0; m < 4; m++) {
            int rbase = m0 + wr * 64 + m * 16 + (lane >> 4) * 4;
#pragma unroll
            for (int r = 0; r < 4; r++)
                if (rbase + r < count)
                    atomicAdd(&hfinC[e * ESTR + rbase + r], s[m][r]);
        }
    }
}

// ---------------------------------------------------------------------------
__global__ __launch_bounds__(256) void k_out(
    const int* __restrict__ lt, const float* __restrict__ yref,
    const float* __restrict__ alpha, const int* __restrict__ rcnt,
    const int* __restrict__ ridxP, const int* __restrict__ post,
    const float* __restrict__ hfinC, float* __restrict__ out) {
    int t = blockIdx.x * 4 + (threadIdx.x >> 6);
    int lane = threadIdx.x & 63;
    if (t >= NTR) return;
    int lab = lt[t];
    int e = lab - 1;
    float ht = hfinC[e * ESTR + post[t]];
    float a = alpha[e];
    int n = rcnt[e];
    const int* lst = ridxP + e * NREF;
    float num = 0.f, den = 0.f;
    for (int i = lane; i < n; i += 64) {
        int pk = lst[i];
        int r = pk & 0xFFFF;
        int pq = pk >> 16;
        float d = fabsf(ht - hfinC[e * ESTR + pq]);
        float p = expf(-a * d);
        num += p * yref[r];
        den += p;
    }
#pragma unroll
    for (int o = 32; o > 0; o >>= 1) {
        num += __shfl_down(num, o, 64);
        den += __shfl_down(den, o, 64);
    }
    if (lane == 0) {
        out[t] = (float)lab;
        out[NTR + t] = num / den;
    }
}

extern "C" void kernel_launch(void* const* d_in, const int* in_sizes, int n_in,
                              void* d_out, int out_size, void* d_ws, size_t ws_size,
                              hipStream_t stream) {
    const float* xr    = (const float*)d_in[0];
    const float* yref  = (const float*)d_in[1];
    const int*   lr    = (const int*)  d_in[2];
    const float* xt    = (const float*)d_in[3];
    const int*   lt    = (const int*)  d_in[4];
    const float* W1    = (const float*)d_in[5];
    const float* b1    = (const float*)d_in[6];
    const float* W2    = (const float*)d_in[7];
    const float* b2    = (const float*)d_in[8];
    const float* W3    = (const float*)d_in[9];
    // d_in[10] = b3 (cancels in |ht-hr|), d_in[11] = alpha
    const float* alpha = (const float*)d_in[11];

    // allow 64KB dynamic LDS (capture-safe host-side attribute, idempotent)
    hipFuncSetAttribute((const void*)k_l1,
                        hipFuncAttributeMaxDynamicSharedMemorySize, 2 * 32768);
    hipFuncSetAttribute((const void*)k_l23,
                        hipFuncAttributeMaxDynamicSharedMemorySize, 2 * 32768);

    char* ws = (char*)d_ws;
    int*   cnt   = (int*)(ws + WS_CNT);
    int*   rcnt  = (int*)(ws + WS_RCNT);
    int*   post  = (int*)(ws + WS_POST);
    int*   ridxP = (int*)(ws + WS_RIDX);
    int*   comb  = (int*)(ws + WS_COMB);
    short* W1Th  = (short*)(ws + WS_W1TH);
    short* W1Tl  = (short*)(ws + WS_W1TL);
    short* XgH   = (short*)(ws + WS_XGH);
    short* XgL   = (short*)(ws + WS_XGL);
    short* W2Th  = (short*)(ws + WS_W2TH);   // aliases XgH (Xg dead after k_l1)
    short* W2Tl  = (short*)(ws + WS_W2TL);   // aliases XgL
    short* H1h   = (short*)(ws + WS_H1H);
    short* H1l   = (short*)(ws + WS_H1L);
    float* hfinC = (float*)(ws + WS_HFIN);
    float* out   = (float*)d_out;

    k_compact<<<1, 1024, 0, stream>>>(lr, lt, cnt, rcnt, comb, ridxP, post);

    k_prep<<<PREP_ZERO, 256, 0, stream>>>(W1, xr, xt, cnt, comb,
                                          W1Th, W1Tl, XgH, XgL, hfinC);

    k_l1<<<8 * MT * NE, 256, 2 * 32768, stream>>>(XgH, XgL, W1Th, W1Tl, b1, cnt,
                                                  H1h, H1l);

    // W2 transpose AFTER k_l1 (it overwrites the Xg region)
    k_tr2<<<dim3(HID / 32, HID / 32, NE), 256, 0, stream>>>(W2, W2Th, W2Tl);

    // l23 in two M-slices (disjoint rows; split for profiling visibility)
    k_l23<<<8 * 14 * NE, 256, 2 * 32768, stream>>>(H1h, H1l, W2Th, W2Tl, b2, W3,
                                                   cnt, hfinC, 0, 14);
    k_l23<<<8 * 13 * NE, 256, 2 * 32768, stream>>>(H1h, H1l, W2Th, W2Tl, b2, W3,
                                                   cnt, hfinC, 14, 13);

    k_out<<<NTR / 4, 256, 0, stream>>>(lt, yref, alpha, rcnt, ridxP, post, hfinC, out);
}

// Round 9
// 276.328 us; speedup vs baseline: 1.5540x; 1.0579x over previous
//
#include <hip/hip_runtime.h>
#include <hip/hip_bf16.h>

#define NREF  4096
#define NTR   8192
#define NCOMB 12288
#define DIN   384
#define HID   1024
#define NE    4
#define ESTR  3456   // per-element compact row stride (count~3072, +pad)
#define MT    (ESTR / 128)   // 27 m-tiles

typedef __attribute__((ext_vector_type(8))) short bf16x8;
typedef __attribute__((ext_vector_type(4))) short s16x4;
typedef __attribute__((ext_vector_type(4))) float f32x4;

__device__ __forceinline__ short f2bf(float f) {
    unsigned u = __builtin_bit_cast(unsigned, f);
    unsigned r = (u + 0x7FFF + ((u >> 16) & 1)) >> 16;   // RNE
    return (short)r;
}
__device__ __forceinline__ float bf2f(short s) {
    unsigned u = ((unsigned)(unsigned short)s) << 16;
    return __builtin_bit_cast(float, u);
}
__device__ __forceinline__ void gload16(const void* g, void* l) {
    __builtin_amdgcn_global_load_lds(
        (const __attribute__((address_space(1))) void*)g,
        (__attribute__((address_space(3))) void*)l, 16, 0, 0);
}
__device__ __forceinline__ float celu1(float v) {
    return v > 0.f ? v : (expf(v) - 1.f);
}

// ---------------------------------------------------------------------------
// Atomic-free compaction: single 1024-thread workgroup, 12 items/thread,
// two-level prefix scan per element bucket. Positions assigned in original
// index order; refs (i<NREF) therefore occupy positions 0..rcnt[e]-1.
__global__ __launch_bounds__(1024) void k_compact(
    const int* __restrict__ lr, const int* __restrict__ lt,
    int* cnt, int* rcnt, int* comb, int* post) {
    int t = threadIdx.x;
    int wid = t >> 6, lane = t & 63;
    int base = t * 12;

    int lab[12];
    int c0 = 0, c1 = 0, c2 = 0, c3 = 0;
    int r0 = 0, r1 = 0, r2 = 0, r3 = 0;
#pragma unroll
    for (int j = 0; j < 12; j++) {
        int i = base + j;
        int l = (i < NREF) ? lr[i] : lt[i - NREF];
        lab[j] = l;
        c0 += (l == 1); c1 += (l == 2); c2 += (l == 3); c3 += (l == 4);
        if (i < NREF) {
            r0 += (l == 1); r1 += (l == 2); r2 += (l == 3); r3 += (l == 4);
        }
    }

    int v0 = c0, v1 = c1, v2 = c2, v3 = c3;
#pragma unroll
    for (int off = 1; off < 64; off <<= 1) {
        int u0 = __shfl_up(v0, off, 64), u1 = __shfl_up(v1, off, 64);
        int u2 = __shfl_up(v2, off, 64), u3 = __shfl_up(v3, off, 64);
        if (lane >= off) { v0 += u0; v1 += u1; v2 += u2; v3 += u3; }
    }
    int s0 = r0, s1 = r1, s2 = r2, s3 = r3;
#pragma unroll
    for (int off = 32; off > 0; off >>= 1) {
        s0 += __shfl_xor(s0, off, 64); s1 += __shfl_xor(s1, off, 64);
        s2 += __shfl_xor(s2, off, 64); s3 += __shfl_xor(s3, off, 64);
    }

    __shared__ int wtot[16][4], woff[16][4], rtot[16][4];
    if (lane == 63) {
        wtot[wid][0] = v0; wtot[wid][1] = v1; wtot[wid][2] = v2; wtot[wid][3] = v3;
    }
    if (lane == 0) {
        rtot[wid][0] = s0; rtot[wid][1] = s1; rtot[wid][2] = s2; rtot[wid][3] = s3;
    }
    __syncthreads();
    if (t == 0) {
        int a0 = 0, a1 = 0, a2 = 0, a3 = 0, b0 = 0, b1 = 0, b2 = 0, b3 = 0;
#pragma unroll
        for (int w = 0; w < 16; w++) {
            woff[w][0] = a0; woff[w][1] = a1; woff[w][2] = a2; woff[w][3] = a3;
            a0 += wtot[w][0]; a1 += wtot[w][1]; a2 += wtot[w][2]; a3 += wtot[w][3];
            b0 += rtot[w][0]; b1 += rtot[w][1]; b2 += rtot[w][2]; b3 += rtot[w][3];
        }
        cnt[0] = a0; cnt[1] = a1; cnt[2] = a2; cnt[3] = a3;
        rcnt[0] = b0; rcnt[1] = b1; rcnt[2] = b2; rcnt[3] = b3;
    }
    __syncthreads();

    int q0 = v0 - c0 + woff[wid][0];
    int q1 = v1 - c1 + woff[wid][1];
    int q2 = v2 - c2 + woff[wid][2];
    int q3 = v3 - c3 + woff[wid][3];

#pragma unroll
    for (int j = 0; j < 12; j++) {
        int i = base + j;
        int l = lab[j];
        int p = (l == 1) ? q0 : (l == 2) ? q1 : (l == 3) ? q2 : q3;
        q0 += (l == 1); q1 += (l == 2); q2 += (l == 3); q3 += (l == 4);
        comb[(l - 1) * NCOMB + p] = i;
        if (i >= NREF) post[i - NREF] = p;
    }
}

// ---------------------------------------------------------------------------
// Fused prep. Block ranges: [0,1536) W1 transpose+split; [1536,1536+tr2N)
// W2 transpose+split (permuted K); then 3456 gather blocks (+yrefC); then 4
// hfin-zero blocks. tr2N = 4096 (fused layout) or 0 (legacy: separate k_tr2).
__global__ __launch_bounds__(256) void k_prep(
    const float* __restrict__ W1, const float* __restrict__ W2,
    const float* __restrict__ xr, const float* __restrict__ xt,
    const float* __restrict__ yref,
    const int* __restrict__ cnt, const int* __restrict__ comb,
    short* __restrict__ W1Th, short* __restrict__ W1Tl,
    short* __restrict__ W2Th, short* __restrict__ W2Tl,
    short* __restrict__ XgH, short* __restrict__ XgL,
    float* __restrict__ yrefC, float* __restrict__ hfinC, int tr2N) {
    __shared__ float s[32][33];
    int b = blockIdx.x;
    if (b < 1536) {
        // W1 [e][K=384][N=1024] -> W1T hi/lo [e][N][K]
        int e = b / 384, r = b % 384;
        int n0 = (r & 31) * 32, k0 = (r >> 5) * 32;
        int tx = threadIdx.x & 31, ty = threadIdx.x >> 5;
        const float* src = W1 + (size_t)e * DIN * HID;
#pragma unroll
        for (int i = 0; i < 32; i += 8)
            s[ty + i][tx] = src[(size_t)(k0 + ty + i) * HID + n0 + tx];
        __syncthreads();
#pragma unroll
        for (int i = 0; i < 32; i += 8) {
            float v = s[tx][ty + i];
            short hb = f2bf(v);
            short lb = f2bf(v - bf2f(hb));
            size_t o = ((size_t)e * HID + n0 + ty + i) * DIN + k0 + tx;
            W1Th[o] = hb;
            W1Tl[o] = lb;
        }
    } else if (b < 1536 + tr2N) {
        // W2 [e][K=1024][N=1024] -> W2T hi/lo [e][N][pi(K)]
        int b2 = b - 1536;
        int e = b2 / 1024, r = b2 % 1024;
        int n0 = (r & 31) * 32, k0 = (r >> 5) * 32;
        int tx = threadIdx.x & 31, ty = threadIdx.x >> 5;
        const float* src = W2 + (size_t)e * HID * HID;
#pragma unroll
        for (int i = 0; i < 32; i += 8)
            s[ty + i][tx] = src[(size_t)(k0 + ty + i) * HID + n0 + tx];
        __syncthreads();
        int k = k0 + tx;
        int kk = (k & ~63) | ((k & 15) << 2) | ((k >> 4) & 3);
#pragma unroll
        for (int i = 0; i < 32; i += 8) {
            float v = s[tx][ty + i];
            short hb = f2bf(v);
            short lb = f2bf(v - bf2f(hb));
            size_t o = ((size_t)e * HID + n0 + ty + i) * HID + kk;
            W2Th[o] = hb;
            W2Tl[o] = lb;
        }
    } else if (b < 1536 + tr2N + 3456) {
        int b2 = b - 1536 - tr2N;
        int e = b2 / (ESTR / 4);
        int m = (b2 % (ESTR / 4)) * 4 + (threadIdx.x >> 6);
        int lane = threadIdx.x & 63;
        size_t dst = ((size_t)e * ESTR + m) * DIN;
        if (m < cnt[e]) {
            int g = comb[e * NCOMB + m];
            const float* src = (g < NREF) ? (xr + (size_t)g * DIN)
                                          : (xt + (size_t)(g - NREF) * DIN);
            if (lane == 0 && g < NREF) yrefC[e * ESTR + m] = yref[g];
#pragma unroll
            for (int c = lane * 2, it = 0; it < 3; c += 128, ++it) {
                float2 v = *(const float2*)(src + c);
                short2 h, l;
                h.x = f2bf(v.x); l.x = f2bf(v.x - bf2f(h.x));
                h.y = f2bf(v.y); l.y = f2bf(v.y - bf2f(h.y));
                *(short2*)(XgH + dst + c) = h;
                *(short2*)(XgL + dst + c) = l;
            }
        } else {
#pragma unroll
            for (int c = lane * 2, it = 0; it < 3; c += 128, ++it) {
                *(short2*)(XgH + dst + c) = short2{0, 0};
                *(short2*)(XgL + dst + c) = short2{0, 0};
            }
        }
    } else {
        int idx = (b - 1536 - tr2N - 3456) * 1024 + threadIdx.x;
        if (idx * 4 < NE * ESTR) {
            f32x4 z = {0.f, 0.f, 0.f, 0.f};
            *(f32x4*)(hfinC + idx * 4) = z;
        }
    }
}

// Legacy-path W2 transpose (aliased region; must run between l1 and l23).
__global__ __launch_bounds__(256) void k_tr2(const float* __restrict__ W,
                                             short* __restrict__ Th,
                                             short* __restrict__ Tl) {
    int e = blockIdx.z;
    __shared__ float s[32][33];
    int tx = threadIdx.x & 31, ty = threadIdx.x >> 5;
    int k0 = blockIdx.y * 32, n0 = blockIdx.x * 32;
    const float* src = W + (size_t)e * HID * HID;
#pragma unroll
    for (int i = 0; i < 32; i += 8)
        s[ty + i][tx] = src[(size_t)(k0 + ty + i) * HID + n0 + tx];
    __syncthreads();
    int k = k0 + tx;
    int kk = (k & ~63) | ((k & 15) << 2) | ((k >> 4) & 3);
#pragma unroll
    for (int i = 0; i < 32; i += 8) {
        float v = s[tx][ty + i];
        short hb = f2bf(v);
        short lb = f2bf(v - bf2f(hb));
        size_t o = ((size_t)e * HID + n0 + ty + i) * HID + kk;
        Th[o] = hb;
        Tl[o] = lb;
    }
}

// ---------------------------------------------------------------------------
#define READ_FRAGS(slotp)                                                     \
    bf16x8 ah[4], al[4], bh[4], bl[4];                                        \
    _Pragma("unroll")                                                         \
    for (int m = 0; m < 4; m++) {                                             \
        int row = wr * 64 + m * 16 + (lane & 15);                             \
        int off = row * 64 + ((((lane >> 4) ^ ((row >> 1) & 3))) << 4);       \
        ah[m] = *(const bf16x8*)((slotp) + off);                              \
        al[m] = *(const bf16x8*)((slotp) + 8192 + off);                       \
    }                                                                         \
    _Pragma("unroll")                                                         \
    for (int n = 0; n < 4; n++) {                                             \
        int row = wc * 64 + n * 16 + (lane & 15);                             \
        int off = row * 64 + ((((lane >> 4) ^ ((row >> 1) & 3))) << 4);       \
        bh[n] = *(const bf16x8*)((slotp) + 16384 + off);                      \
        bl[n] = *(const bf16x8*)((slotp) + 24576 + off);                      \
    }

#define DO_MFMA()                                                             \
    __builtin_amdgcn_s_setprio(1);                                            \
    _Pragma("unroll")                                                         \
    for (int m = 0; m < 4; m++)                                               \
        _Pragma("unroll")                                                     \
        for (int n = 0; n < 4; n++) {                                         \
            acc[m][n] = __builtin_amdgcn_mfma_f32_16x16x32_bf16(ah[m], bh[n], acc[m][n], 0, 0, 0); \
            acc[m][n] = __builtin_amdgcn_mfma_f32_16x16x32_bf16(al[m], bh[n], acc[m][n], 0, 0, 0); \
            acc[m][n] = __builtin_amdgcn_mfma_f32_16x16x32_bf16(ah[m], bl[n], acc[m][n], 0, 0, 0); \
        }                                                                     \
    __builtin_amdgcn_s_setprio(0);

// 2-slot double buffer; STAGE(t+1) issued BEFORE compute(t); one barrier/iter.
#define PIPE_LOOP(NT, STAGE)                                                  \
    STAGE(0, 0);                                                              \
    for (int kt = 0; kt < (NT); ++kt) {                                       \
        __builtin_amdgcn_sched_barrier(0);                                    \
        asm volatile("s_waitcnt vmcnt(0)" ::: "memory");                      \
        __builtin_amdgcn_s_barrier();                                         \
        __builtin_amdgcn_sched_barrier(0);                                    \
        if (kt + 1 < (NT)) STAGE(kt + 1, (kt + 1) & 1);                       \
        char* slotp = smem + (kt & 1) * 32768;                                \
        READ_FRAGS(slotp)                                                     \
        DO_MFMA()                                                             \
    }

// ---------------------------------------------------------------------------
// Layer 1: H1C = celu(Xg @ W1 + b1). 128x128 tile, BK=32, 4 waves.
__global__ __launch_bounds__(256) void k_l1(
    const short* __restrict__ XgH, const short* __restrict__ XgL,
    const short* __restrict__ W1Th, const short* __restrict__ W1Tl,
    const float* __restrict__ b1, const int* __restrict__ cnt,
    short* __restrict__ H1h, short* __restrict__ H1l) {
    int bid = blockIdx.x;
    int n0 = (bid & 7) * 128;
    int rest = bid >> 3;
    int e = rest / MT;
    int count = cnt[e];
    int m0 = (rest % MT) * 128;
    if (m0 >= count) return;

    extern __shared__ __align__(16) char smem[];   // 2 * 32768
    int t = threadIdx.x, w = t >> 6, lane = t & 63;
    int wr = w >> 1, wc = w & 1;

    int srow = t >> 2, sx = t & 3, fB = (srow >> 1) & 3;
    size_t aoff0 = ((size_t)e * ESTR + m0 + srow) * DIN + (sx ^ fB) * 8;
    size_t aoff1 = aoff0 + (size_t)64 * DIN;
    size_t boff0 = ((size_t)e * HID + n0 + srow) * DIN + (sx ^ fB) * 8;
    size_t boff1 = boff0 + (size_t)64 * DIN;
    char* ldsW = smem + w * 1024;   // wave-uniform base; HW adds lane*16

#define STAGE1(T, SL) do { int kk = (T) * 32; char* Ld = ldsW + (SL) * 32768; \
        gload16(XgH  + aoff0 + kk, Ld + 0);     gload16(XgH  + aoff1 + kk, Ld + 4096);  \
        gload16(XgL  + aoff0 + kk, Ld + 8192);  gload16(XgL  + aoff1 + kk, Ld + 12288); \
        gload16(W1Th + boff0 + kk, Ld + 16384); gload16(W1Th + boff1 + kk, Ld + 20480); \
        gload16(W1Tl + boff0 + kk, Ld + 24576); gload16(W1Tl + boff1 + kk, Ld + 28672); } while (0)

    f32x4 acc[4][4] = {};
    PIPE_LOOP(DIN / 32, STAGE1)
#undef STAGE1

    int q = lane & 15;
    float bb[4];
#pragma unroll
    for (int n = 0; n < 4; n++) bb[n] = b1[e * HID + n0 + wc * 64 + n * 16 + q];
#pragma unroll
    for (int m = 0; m < 4; m++) {
        int rbase = m0 + wr * 64 + m * 16 + (lane >> 4) * 4;
#pragma unroll
        for (int r = 0; r < 4; r++) {
            int row = rbase + r;
            if (row < count) {
                s16x4 hv, lv;
#pragma unroll
                for (int n = 0; n < 4; n++) {
                    float v = celu1(acc[m][n][r] + bb[n]);
                    hv[n] = f2bf(v);
                    lv[n] = f2bf(v - bf2f(hv[n]));
                }
                size_t o = ((size_t)e * ESTR + row) * HID + n0 + wc * 64 + q * 4;
                *(s16x4*)(H1h + o) = hv;
                *(s16x4*)(H1l + o) = lv;
            }
        }
    }
}

// ---------------------------------------------------------------------------
// Layers 2+3 fused: hfinC += sum_col celu(H1C@W2[:,col]+b2[col])*W3[col]
__global__ __launch_bounds__(256) void k_l23(
    const short* __restrict__ H1h, const short* __restrict__ H1l,
    const short* __restrict__ W2Th, const short* __restrict__ W2Tl,
    const float* __restrict__ b2, const float* __restrict__ W3,
    const int* __restrict__ cnt, float* __restrict__ hfinC) {
    int bid = blockIdx.x;
    int n0 = (bid & 7) * 128;
    int rest = bid >> 3;
    int e = rest / MT;
    int count = cnt[e];
    int m0 = (rest % MT) * 128;
    if (m0 >= count) return;

    extern __shared__ __align__(16) char smem[];   // 2 * 32768
    int t = threadIdx.x, w = t >> 6, lane = t & 63;
    int wr = w >> 1, wc = w & 1;

    int srow = t >> 2, sx = t & 3, f0 = (srow >> 1) & 3;
    size_t aoff0 = ((size_t)e * ESTR + m0 + srow) * HID + (sx ^ f0) * 8;
    size_t aoff1 = aoff0 + (size_t)64 * HID;
    size_t boff0 = ((size_t)e * HID + n0 + srow) * HID + (sx ^ f0) * 8;
    size_t boff1 = boff0 + (size_t)64 * HID;
    char* ldsW = smem + w * 1024;

#define STAGE23(T, SL) do { int kk = (T) * 32; char* Ld = ldsW + (SL) * 32768; \
        gload16(H1h  + aoff0 + kk, Ld + 0);     gload16(H1h  + aoff1 + kk, Ld + 4096);  \
        gload16(H1l  + aoff0 + kk, Ld + 8192);  gload16(H1l  + aoff1 + kk, Ld + 12288); \
        gload16(W2Th + boff0 + kk, Ld + 16384); gload16(W2Th + boff1 + kk, Ld + 20480); \
        gload16(W2Tl + boff0 + kk, Ld + 24576); gload16(W2Tl + boff1 + kk, Ld + 28672); } while (0)

    f32x4 acc[4][4] = {};
    PIPE_LOOP(HID / 32, STAGE23)
#undef STAGE23

    float s[4][4] = {};
#pragma unroll
    for (int n = 0; n < 4; n++) {
        int col = n0 + wc * 64 + n * 16 + (lane & 15);
        float bbv = b2[e * HID + col];
        float w3 = W3[e * HID + col];
#pragma unroll
        for (int m = 0; m < 4; m++)
#pragma unroll
            for (int r = 0; r < 4; r++)
                s[m][r] += celu1(acc[m][n][r] + bbv) * w3;
    }
#pragma unroll
    for (int m = 0; m < 4; m++)
#pragma unroll
        for (int r = 0; r < 4; r++) {
#pragma unroll
            for (int off = 8; off > 0; off >>= 1)
                s[m][r] += __shfl_xor(s[m][r], off, 64);
        }
    if ((lane & 15) == 0) {
#pragma unroll
        for (int m = 0; m < 4; m++) {
            int rbase = m0 + wr * 64 + m * 16 + (lane >> 4) * 4;
#pragma unroll
            for (int r = 0; r < 4; r++)
                if (rbase + r < count)
                    atomicAdd(&hfinC[e * ESTR + rbase + r], s[m][r]);
        }
    }
}

// ---------------------------------------------------------------------------
// Final: fully-coalesced streaming over compact ref range [0, rcnt[e]).
__global__ __launch_bounds__(256) void k_out(
    const int* __restrict__ lt, const float* __restrict__ alpha,
    const int* __restrict__ rcnt, const int* __restrict__ post,
    const float* __restrict__ hfinC, const float* __restrict__ yrefC,
    float* __restrict__ out) {
    int t = blockIdx.x * 4 + (threadIdx.x >> 6);
    int lane = threadIdx.x & 63;
    if (t >= NTR) return;
    int lab = lt[t];
    int e = lab - 1;
    float ht = hfinC[e * ESTR + post[t]];
    float a = alpha[e];
    int n = rcnt[e];
    const float* hb = hfinC + e * ESTR;
    const float* yb = yrefC + e * ESTR;
    float num = 0.f, den = 0.f;
    for (int i = lane; i < n; i += 64) {
        float d = fabsf(ht - hb[i]);
        float p = expf(-a * d);
        num += p * yb[i];
        den += p;
    }
#pragma unroll
    for (int o = 32; o > 0; o >>= 1) {
        num += __shfl_down(num, o, 64);
        den += __shfl_down(den, o, 64);
    }
    if (lane == 0) {
        out[t] = (float)lab;
        out[NTR + t] = num / den;
    }
}

extern "C" void kernel_launch(void* const* d_in, const int* in_sizes, int n_in,
                              void* d_out, int out_size, void* d_ws, size_t ws_size,
                              hipStream_t stream) {
    const float* xr    = (const float*)d_in[0];
    const float* yref  = (const float*)d_in[1];
    const int*   lr    = (const int*)  d_in[2];
    const float* xt    = (const float*)d_in[3];
    const int*   lt    = (const int*)  d_in[4];
    const float* W1    = (const float*)d_in[5];
    const float* b1    = (const float*)d_in[6];
    const float* W2    = (const float*)d_in[7];
    const float* b2    = (const float*)d_in[8];
    const float* W3    = (const float*)d_in[9];
    // d_in[10] = b3 (cancels in |ht-hr|), d_in[11] = alpha
    const float* alpha = (const float*)d_in[11];

    hipFuncSetAttribute((const void*)k_l1,
                        hipFuncAttributeMaxDynamicSharedMemorySize, 2 * 32768);
    hipFuncSetAttribute((const void*)k_l23,
                        hipFuncAttributeMaxDynamicSharedMemorySize, 2 * 32768);

    // ---- ws layout (runtime-selected: fused W2T region vs legacy alias) ----
    const size_t SZ_W1T = (size_t)NE * DIN * HID * 2;   // 3145728 per plane
    const size_t SZ_XG  = (size_t)NE * ESTR * DIN * 2;  // 10616832 per plane
    const size_t SZ_W2T = (size_t)NE * HID * HID * 2;   // 8388608 per plane
    const size_t SZ_H1  = (size_t)NE * ESTR * HID * 2;  // 28311552 per plane

    char* ws = (char*)d_ws;
    int*   cnt   = (int*)(ws + 0);
    int*   rcnt  = (int*)(ws + 16);
    int*   post  = (int*)(ws + 256);
    int*   comb  = (int*)(ws + 256 + (size_t)NTR * 4);
    size_t off = 262144;
    short* W1Th = (short*)(ws + off); off += SZ_W1T;
    short* W1Tl = (short*)(ws + off); off += SZ_W1T;
    short* XgH  = (short*)(ws + off); off += SZ_XG;
    short* XgL  = (short*)(ws + off); off += SZ_XG;

    size_t fusedNeed = off + 2 * SZ_W2T + 2 * SZ_H1 + 2 * (size_t)NE * ESTR * 4;
    bool fused = ws_size >= fusedNeed;

    short *W2Th, *W2Tl;
    if (fused) {
        W2Th = (short*)(ws + off); off += SZ_W2T;
        W2Tl = (short*)(ws + off); off += SZ_W2T;
    } else {
        W2Th = XgH;   // legacy alias: Xg dead after k_l1
        W2Tl = XgL;
    }
    short* H1h  = (short*)(ws + off); off += SZ_H1;
    short* H1l  = (short*)(ws + off); off += SZ_H1;
    float* hfinC = (float*)(ws + off); off += (size_t)NE * ESTR * 4;
    float* yrefC = (float*)(ws + off);
    float* out   = (float*)d_out;

    int tr2N = fused ? 4096 : 0;

    k_compact<<<1, 1024, 0, stream>>>(lr, lt, cnt, rcnt, comb, post);

    k_prep<<<1536 + tr2N + 3456 + 4, 256, 0, stream>>>(
        W1, W2, xr, xt, yref, cnt, comb,
        W1Th, W1Tl, W2Th, W2Tl, XgH, XgL, yrefC, hfinC, tr2N);

    k_l1<<<8 * MT * NE, 256, 2 * 32768, stream>>>(XgH, XgL, W1Th, W1Tl, b1, cnt,
                                                  H1h, H1l);

    if (!fused)   // legacy: W2 transpose must run after k_l1 (aliased region)
        k_tr2<<<dim3(HID / 32, HID / 32, NE), 256, 0, stream>>>(W2, W2Th, W2Tl);

    k_l23<<<8 * MT * NE, 256, 2 * 32768, stream>>>(H1h, H1l, W2Th, W2Tl, b2, W3,
                                                   cnt, hfinC);

    k_out<<<NTR / 4, 256, 0, stream>>>(lt, alpha, rcnt, post, hfinC, yrefC, out);
}